// Round 13
// baseline (284.229 us; speedup 1.0000x reference)
//
#include <hip/hip_runtime.h>
#include <math.h>

#define B_ 4
#define T_ 128
#define C_ 128
#define HW_ 576
#define P_ 32
#define FF_ 512
#define EPS_ATTN 1e-6f
#define EPS_LN 1e-5f
#define TOK 64

typedef __bf16 bf16x8 __attribute__((ext_vector_type(8)));
typedef float f32x4 __attribute__((ext_vector_type(4)));
typedef short s16x8 __attribute__((ext_vector_type(8)));
typedef short s16x4 __attribute__((ext_vector_type(4)));

// ---- ws byte offsets (16B aligned) ----
#define WS_KVT   0        // bf16 [128][32] : kvt[col][d] = KV[col>>5][d][col&31]
#define WS_KSUM  8192     // f32  [128]
#define WS_WQX   8704     // bf16 [128][128]  (x-part of Wq)
#define WS_W1    41472    // bf16 [512][128]
#define WS_W2    172544   // bf16 [128][512]
#define WS_QG    303616   // f32  [512][128]  (guidance projection + bq)

// native RTNE bf16 cvt (compiler packs pairs into v_cvt_pk_bf16_f32)
__device__ __forceinline__ short f2b(float f) {
    return __builtin_bit_cast(short, (__bf16)f);
}
__device__ __forceinline__ float b2f(short s) {
    return __builtin_bit_cast(float, ((unsigned)(unsigned short)s) << 16);
}
// swizzled short-index into [64][128] bf16 tile: XOR 16B granule by (row&7)
__device__ __forceinline__ int swz(int row, int col) {
    return (row << 7) | (col ^ ((row & 7) << 3));
}
// sigmoid-form GELU: v * sigmoid(1.702 v). |err| <= ~0.02 pointwise on h;
// after W2 (random-sign weights, s=0.02) contributes ~0.004 to out.
__device__ __forceinline__ float gelu_f(float v) {
    float e = __expf(-1.702f * v);
    return v * __builtin_amdgcn_rcpf(1.f + e);
}

// ---------------------------------------------------------------------------
// prep: bid 0..143   vectorized weight conversion (4 elems/thread)
//       bid 144..399 guidance projection qg[bt][f] (2 bt per block)
//       bid 400..403 prototypes -> kvt + ksum, split per head (4-way)
// ---------------------------------------------------------------------------
__global__ __launch_bounds__(256)
void prep_all(const float* __restrict__ protos,
              const float* __restrict__ Wk, const float* __restrict__ bk,
              const float* __restrict__ Wv, const float* __restrict__ bv,
              const float* __restrict__ Wq, const float* __restrict__ W1,
              const float* __restrict__ W2, const float* __restrict__ guid,
              const float* __restrict__ bq, char* __restrict__ wsb) {
    __shared__ float smG[256];
    __shared__ float kf_s[P_][32];
    __shared__ float vv_s[P_][32];
    const int bid = blockIdx.x, tid = threadIdx.x;
    if (bid < 144) {
        int idx = bid * 256 + tid;           // 36864 total, 4 elems each
        const float* src;
        short* dst;
        if (idx < 4096) {
            int e = idx * 4;
            src = Wq + ((e >> 7) * 256) + (e & 127);
            dst = (short*)(wsb + WS_WQX) + e;
        } else if (idx < 20480) {
            int e = (idx - 4096) * 4;
            src = W1 + e;
            dst = (short*)(wsb + WS_W1) + e;
        } else {
            int e = (idx - 20480) * 4;
            src = W2 + e;
            dst = (short*)(wsb + WS_W2) + e;
        }
        float4 v = *(const float4*)src;
        s16x4 pk;
        pk[0] = f2b(v.x); pk[1] = f2b(v.y); pk[2] = f2b(v.z); pk[3] = f2b(v.w);
        *(s16x4*)dst = pk;
    } else if (bid < 400) {
        int bt = (bid - 144) * 2 + (tid >> 7);
        int f = tid & 127;
        smG[tid] = guid[(size_t)bt * 128 + f];
        __syncthreads();
        const float* wr = Wq + (size_t)f * 256 + 128;
        const float* gg = &smG[(tid >> 7) * 128];
        float acc = bq[f];
        #pragma unroll
        for (int g = 0; g < 128; g += 4) {
            float4 w4 = *(const float4*)(wr + g);
            acc = fmaf(gg[g],     w4.x, acc);
            acc = fmaf(gg[g + 1], w4.y, acc);
            acc = fmaf(gg[g + 2], w4.z, acc);
            acc = fmaf(gg[g + 3], w4.w, acc);
        }
        ((float*)(wsb + WS_QG))[(size_t)bt * 128 + f] = acc;
    } else {
        // prototypes, head h: cols [32h, 32h+32)
        const int h = bid - 400;
        const int base_c = h * 32;
        const int cl = tid & 31, p0 = tid >> 5;   // p0 in 0..7
        const int c = base_c + cl;
        const float* wkr = Wk + (size_t)c * C_;
        const float* wvr = Wv + (size_t)c * C_;
        float ka[4], va[4];
        #pragma unroll
        for (int i = 0; i < 4; ++i) { ka[i] = bk[c]; va[i] = bv[c]; }
        for (int j = 0; j < C_; j += 4) {
            float4 wk4 = *(const float4*)(wkr + j);
            float4 wv4 = *(const float4*)(wvr + j);
            #pragma unroll
            for (int i = 0; i < 4; ++i) {
                float4 pv = *(const float4*)(protos + (size_t)(p0 + 8 * i) * C_ + j);
                ka[i] = fmaf(pv.x, wk4.x, ka[i]); ka[i] = fmaf(pv.y, wk4.y, ka[i]);
                ka[i] = fmaf(pv.z, wk4.z, ka[i]); ka[i] = fmaf(pv.w, wk4.w, ka[i]);
                va[i] = fmaf(pv.x, wv4.x, va[i]); va[i] = fmaf(pv.y, wv4.y, va[i]);
                va[i] = fmaf(pv.z, wv4.z, va[i]); va[i] = fmaf(pv.w, wv4.w, va[i]);
            }
        }
        #pragma unroll
        for (int i = 0; i < 4; ++i) {
            int p = p0 + 8 * i;
            kf_s[p][cl] = ka[i] > 0.f ? ka[i] + 1.f : __expf(ka[i]);
            vv_s[p][cl] = va[i] * (1.f / P_);
        }
        __syncthreads();
        short* kvt = (short*)(wsb + WS_KVT);
        float* ks  = (float*)(wsb + WS_KSUM);
        #pragma unroll
        for (int o = tid; o < 1024; o += 256) {
            int col = o >> 5, d = o & 31;
            float acc = 0.f;
            for (int p = 0; p < P_; ++p)
                acc = fmaf(kf_s[p][d], vv_s[p][col], acc);
            kvt[(base_c + col) * 32 + d] = f2b(acc);
        }
        if (tid < 32) {
            float acc = 0.f;
            for (int p = 0; p < P_; ++p) acc += kf_s[p][tid];
            ks[base_c + tid] = acc;
        }
    }
}

// ---------------------------------------------------------------------------
// main: round-11 champion structure; staging writes bank-spread via jj
// rotation; dead final FFN barrier removed.
// 64 tokens/block, 8 waves; wave w owns features [16w, 16w+16).
// Swapped MFMAs: D'[feat][tok] = W(A) x act(B).
// ---------------------------------------------------------------------------
__global__ __launch_bounds__(512, 8)
void cat_main(const float* __restrict__ x,
              const float* __restrict__ ln1_g, const float* __restrict__ ln1_b,
              const float* __restrict__ ln2_g, const float* __restrict__ ln2_b,
              const float* __restrict__ b1, const float* __restrict__ b2,
              const char* __restrict__ wsb, float* __restrict__ out) {
    __shared__ short bufA[TOK * C_];   // x -> y
    __shared__ short bufB[TOK * C_];   // qf -> h chunks
    __shared__ float mu1[TOK], rs1[TOK];
    __shared__ float zp[TOK][8];
    __shared__ float lnS[TOK][8], lnS2[TOK][8];

    const short* kvt  = (const short*)(wsb + WS_KVT);
    const float* ksum = (const float*)(wsb + WS_KSUM);
    const short* wqx  = (const short*)(wsb + WS_WQX);
    const short* w1b  = (const short*)(wsb + WS_W1);
    const short* w2b  = (const short*)(wsb + WS_W2);
    const float* qg_g = (const float*)(wsb + WS_QG);

    const int tid = threadIdx.x;
    const int w = tid >> 6, l = tid & 63;
    const int lr = l & 15, lg = l >> 4;
    const int bt = blockIdx.z * T_ + blockIdx.y;
    const int hw0 = blockIdx.x * TOK;
    const int frow = w * 16 + lr;          // A-operand feature row
    const int cb0 = w * 16 + lg * 4;       // D-frag feature base

    // ---- stage x -> bufA: 4-chan x 4-tok register tile, b64 writes.
    //      jj rotation spreads row&7 over 8 values per instruction
    //      (was 2 -> ~16-way bank conflict; now ~4-way). ----
    {
        int cb = tid >> 4, tg = tid & 15;
        float4 v[4];
        #pragma unroll
        for (int i = 0; i < 4; ++i)
            v[i] = *(const float4*)(x + ((size_t)bt * C_ + cb * 4 + i) * HW_
                                    + hw0 + tg * 4);
        #pragma unroll
        for (int j = 0; j < 4; ++j) {
            int jj = (j + (tg >> 1)) & 3;
            s16x4 pk;
            pk[0] = f2b(((const float*)&v[0])[jj]);
            pk[1] = f2b(((const float*)&v[1])[jj]);
            pk[2] = f2b(((const float*)&v[2])[jj]);
            pk[3] = f2b(((const float*)&v[3])[jj]);
            *(s16x4*)&bufA[swz(tg * 4 + jj, cb * 4)] = pk;
        }
    }
    __syncthreads();

    // ---- LN1 stats: 8 threads/token ----
    {
        int tok = tid >> 3, q = tid & 7;
        float s = 0.f, s2 = 0.f;
        #pragma unroll
        for (int j = 0; j < 2; ++j) {
            s16x8 v8 = *(const s16x8*)&bufA[swz(tok, q * 16 + j * 8)];
            #pragma unroll
            for (int e = 0; e < 8; ++e) {
                float v = b2f(v8[e]); s += v; s2 = fmaf(v, v, s2);
            }
        }
        s += __shfl_xor(s, 1); s2 += __shfl_xor(s2, 1);
        s += __shfl_xor(s, 2); s2 += __shfl_xor(s2, 2);
        s += __shfl_xor(s, 4); s2 += __shfl_xor(s2, 4);
        if (q == 0) {
            float mu = s * (1.f / C_);
            mu1[tok] = mu;
            rs1[tok] = rsqrtf(s2 * (1.f / C_) - mu * mu + EPS_LN);
        }
    }

    // ---- Q projection (x part; guidance part precomputed in qg_g) ----
    f32x4 qacc[4];
    #pragma unroll
    for (int mt = 0; mt < 4; ++mt) qacc[mt] = (f32x4){0.f, 0.f, 0.f, 0.f};
    #pragma unroll
    for (int kc = 0; kc < 4; ++kc) {
        bf16x8 aw = *(const bf16x8*)&wqx[frow * C_ + kc * 32 + lg * 8];
        #pragma unroll
        for (int mt = 0; mt < 4; ++mt) {
            bf16x8 bx = *(const bf16x8*)&bufA[swz(mt * 16 + lr, kc * 32 + lg * 8)];
            qacc[mt] = __builtin_amdgcn_mfma_f32_16x16x32_bf16(aw, bx, qacc[mt], 0, 0, 0);
        }
    }

    // ---- qf = elu(q + qg)+1 -> bufB (b64), Z partials ----
    {
        f32x4 qg4 = *(const f32x4*)&qg_g[(size_t)bt * C_ + cb0];
        f32x4 ks4 = *(const f32x4*)&ksum[cb0];
        #pragma unroll
        for (int mt = 0; mt < 4; ++mt) {
            float dp = 0.f;
            s16x4 pk;
            #pragma unroll
            for (int r = 0; r < 4; ++r) {
                float qv = qacc[mt][r] + qg4[r];
                float f = qv > 0.f ? qv + 1.f : __expf(qv);
                dp = fmaf(f, ks4[r], dp);
                pk[r] = f2b(f);
            }
            *(s16x4*)&bufB[swz(mt * 16 + lr, cb0)] = pk;
            dp += __shfl_xor(dp, 16);
            dp += __shfl_xor(dp, 32);
            if (lg == 0) zp[mt * 16 + lr][w] = dp;
        }
    }
    __syncthreads();

    // ---- attention: K=32 (head w>>1) ----
    f32x4 aacc[4];
    {
        const int h = w >> 1;
        bf16x8 aw = *(const bf16x8*)&kvt[frow * 32 + lg * 8];
        #pragma unroll
        for (int mt = 0; mt < 4; ++mt) {
            bf16x8 bq_ = *(const bf16x8*)&bufB[swz(mt * 16 + lr, h * 32 + lg * 8)];
            aacc[mt] = __builtin_amdgcn_mfma_f32_16x16x32_bf16(
                aw, bq_, (f32x4){0.f, 0.f, 0.f, 0.f}, 0, 0, 0);
        }
    }

    // ---- o1 = attn*Z + LN1(x); LN2 partials ----
    f32x4 o1[4];
    {
        f32x4 g1 = *(const f32x4*)&ln1_g[cb0];
        f32x4 bb1 = *(const f32x4*)&ln1_b[cb0];
        #pragma unroll
        for (int mt = 0; mt < 4; ++mt) {
            int tok = mt * 16 + lr;
            f32x4 za = *(const f32x4*)&zp[tok][0];
            f32x4 zb = *(const f32x4*)&zp[tok][4];
            float den = za[0] + za[1] + za[2] + za[3]
                      + zb[0] + zb[1] + zb[2] + zb[3] + EPS_ATTN;
            float zv = (float)P_ * __builtin_amdgcn_rcpf(den);
            s16x4 xv = *(const s16x4*)&bufA[swz(tok, cb0)];
            float mu = mu1[tok], rs = rs1[tok];
            float s = 0.f, s2 = 0.f;
            #pragma unroll
            for (int r = 0; r < 4; ++r) {
                float ln1 = fmaf((b2f(xv[r]) - mu) * rs, g1[r], bb1[r]);
                float v = fmaf(aacc[mt][r], zv, ln1);
                o1[mt][r] = v;
                s += v; s2 = fmaf(v, v, s2);
            }
            s += __shfl_xor(s, 16); s2 += __shfl_xor(s2, 16);
            s += __shfl_xor(s, 32); s2 += __shfl_xor(s2, 32);
            if (lg == 0) { lnS[tok][w] = s; lnS2[tok][w] = s2; }
        }
    }
    __syncthreads();

    // ---- y = LN2(o1) -> bufA ----
    {
        f32x4 g2 = *(const f32x4*)&ln2_g[cb0];
        f32x4 bb2 = *(const f32x4*)&ln2_b[cb0];
        #pragma unroll
        for (int mt = 0; mt < 4; ++mt) {
            int tok = mt * 16 + lr;
            f32x4 sa = *(const f32x4*)&lnS[tok][0];
            f32x4 sb = *(const f32x4*)&lnS[tok][4];
            f32x4 pa = *(const f32x4*)&lnS2[tok][0];
            f32x4 pb = *(const f32x4*)&lnS2[tok][4];
            float ss = sa[0] + sa[1] + sa[2] + sa[3] + sb[0] + sb[1] + sb[2] + sb[3];
            float ss2 = pa[0] + pa[1] + pa[2] + pa[3] + pb[0] + pb[1] + pb[2] + pb[3];
            float mu = ss * (1.f / C_);
            float rs = rsqrtf(ss2 * (1.f / C_) - mu * mu + EPS_LN);
            s16x4 pk;
            #pragma unroll
            for (int r = 0; r < 4; ++r)
                pk[r] = f2b(fmaf((o1[mt][r] - mu) * rs, g2[r], bb2[r]));
            *(s16x4*)&bufA[swz(tok, cb0)] = pk;
        }
    }
    __syncthreads();

    // ---- FFN ----
    f32x4 facc[4];
    {
        f32x4 bv2 = *(const f32x4*)&b2[cb0];
        #pragma unroll
        for (int mt = 0; mt < 4; ++mt)
            #pragma unroll
            for (int r = 0; r < 4; ++r)
                facc[mt][r] = o1[mt][r] + bv2[r];
    }
    for (int ch = 0; ch < 4; ++ch) {
        f32x4 hacc[4];
        #pragma unroll
        for (int mt = 0; mt < 4; ++mt) hacc[mt] = (f32x4){0.f, 0.f, 0.f, 0.f};
        #pragma unroll
        for (int kc = 0; kc < 4; ++kc) {
            bf16x8 aw = *(const bf16x8*)&w1b[(ch * 128 + frow) * C_ + kc * 32 + lg * 8];
            #pragma unroll
            for (int mt = 0; mt < 4; ++mt) {
                bf16x8 by = *(const bf16x8*)&bufA[swz(mt * 16 + lr, kc * 32 + lg * 8)];
                hacc[mt] = __builtin_amdgcn_mfma_f32_16x16x32_bf16(aw, by, hacc[mt], 0, 0, 0);
            }
        }
        f32x4 bb = *(const f32x4*)&b1[ch * 128 + cb0];
        #pragma unroll
        for (int mt = 0; mt < 4; ++mt) {
            s16x4 pk;
            #pragma unroll
            for (int r = 0; r < 4; ++r)
                pk[r] = f2b(gelu_f(hacc[mt][r] + bb[r]));
            *(s16x4*)&bufB[swz(mt * 16 + lr, cb0)] = pk;
        }
        __syncthreads();
        #pragma unroll
        for (int kc = 0; kc < 4; ++kc) {
            bf16x8 aw = *(const bf16x8*)&w2b[frow * FF_ + ch * 128 + kc * 32 + lg * 8];
            #pragma unroll
            for (int mt = 0; mt < 4; ++mt) {
                bf16x8 bh = *(const bf16x8*)&bufB[swz(mt * 16 + lr, kc * 32 + lg * 8)];
                facc[mt] = __builtin_amdgcn_mfma_f32_16x16x32_bf16(aw, bh, facc[mt], 0, 0, 0);
            }
        }
        if (ch < 3) __syncthreads();   // last barrier is dead: epilogue reads no LDS
    }

    // ---- epilogue (facc = o1 + ffn + b2); champion mt-outer order ----
    #pragma unroll
    for (int mt = 0; mt < 4; ++mt) {
        int tok = mt * 16 + lr;
        #pragma unroll
        for (int r = 0; r < 4; ++r)
            out[((size_t)bt * C_ + cb0 + r) * HW_ + hw0 + tok] = facc[mt][r];
    }
}

extern "C" void kernel_launch(void* const* d_in, const int* in_sizes, int n_in,
                              void* d_out, int out_size, void* d_ws, size_t ws_size,
                              hipStream_t stream) {
    (void)in_sizes; (void)n_in; (void)out_size; (void)ws_size;
    const float* x      = (const float*)d_in[0];
    const float* guid   = (const float*)d_in[1];
    const float* protos = (const float*)d_in[2];
    const float* Wq     = (const float*)d_in[3];
    const float* bq     = (const float*)d_in[4];
    const float* Wk     = (const float*)d_in[5];
    const float* bk     = (const float*)d_in[6];
    const float* Wv     = (const float*)d_in[7];
    const float* bv     = (const float*)d_in[8];
    const float* ln1_g  = (const float*)d_in[9];
    const float* ln1_b  = (const float*)d_in[10];
    const float* ln2_g  = (const float*)d_in[11];
    const float* ln2_b  = (const float*)d_in[12];
    const float* W1     = (const float*)d_in[13];
    const float* b1     = (const float*)d_in[14];
    const float* W2     = (const float*)d_in[15];
    const float* b2     = (const float*)d_in[16];
    float* out = (float*)d_out;
    char* wsb  = (char*)d_ws;

    prep_all<<<404, 256, 0, stream>>>(protos, Wk, bk, Wv, bv, Wq, W1, W2,
                                      guid, bq, wsb);
    dim3 grid(HW_ / TOK, T_, B_);
    cat_main<<<grid, 512, 0, stream>>>(x, ln1_g, ln1_b, ln2_g, ln2_b,
                                       b1, b2, wsb, out);
}

// Round 14
// 239.038 us; speedup vs baseline: 1.1891x; 1.1891x over previous
//
#include <hip/hip_runtime.h>
#include <math.h>

#define B_ 4
#define T_ 128
#define C_ 128
#define HW_ 576
#define P_ 32
#define FF_ 512
#define EPS_ATTN 1e-6f
#define EPS_LN 1e-5f
#define TOK 64

typedef __bf16 bf16x8 __attribute__((ext_vector_type(8)));
typedef float f32x4 __attribute__((ext_vector_type(4)));
typedef short s16x8 __attribute__((ext_vector_type(8)));
typedef short s16x4 __attribute__((ext_vector_type(4)));

// ---- ws byte offsets (16B aligned) ----
#define WS_KVT   0        // bf16 [128][32] : kvt[col][d] = KV[col>>5][d][col&31]
#define WS_KSUM  8192     // f32  [128]
#define WS_WQX   8704     // bf16 [128][128]  (x-part of Wq)
#define WS_W1    41472    // bf16 [512][128]
#define WS_W2    172544   // bf16 [128][512]
#define WS_QG    303616   // f32  [512][128]  (guidance projection + bq)

// native RTNE bf16 cvt (compiler packs pairs into v_cvt_pk_bf16_f32)
__device__ __forceinline__ short f2b(float f) {
    return __builtin_bit_cast(short, (__bf16)f);
}
__device__ __forceinline__ float b2f(short s) {
    return __builtin_bit_cast(float, ((unsigned)(unsigned short)s) << 16);
}
// swizzled short-index into [64][128] bf16 tile: XOR 16B granule by (row&7)
__device__ __forceinline__ int swz(int row, int col) {
    return (row << 7) | (col ^ ((row & 7) << 3));
}
// sigmoid-form GELU: v * sigmoid(1.702 v). |err| <= ~0.02 pointwise on h;
// after W2 (random-sign weights, s=0.02) contributes ~0.004 to out.
__device__ __forceinline__ float gelu_f(float v) {
    float e = __expf(-1.702f * v);
    return v * __builtin_amdgcn_rcpf(1.f + e);
}

// ---------------------------------------------------------------------------
// prep: bid 0..143   vectorized weight conversion (4 elems/thread)
//       bid 144..399 guidance projection qg[bt][f] (2 bt per block)
//       bid 400..403 prototypes -> kvt + ksum, split per head (4-way)
// ---------------------------------------------------------------------------
__global__ __launch_bounds__(256)
void prep_all(const float* __restrict__ protos,
              const float* __restrict__ Wk, const float* __restrict__ bk,
              const float* __restrict__ Wv, const float* __restrict__ bv,
              const float* __restrict__ Wq, const float* __restrict__ W1,
              const float* __restrict__ W2, const float* __restrict__ guid,
              const float* __restrict__ bq, char* __restrict__ wsb) {
    __shared__ float smG[256];
    __shared__ float kf_s[P_][32];
    __shared__ float vv_s[P_][32];
    const int bid = blockIdx.x, tid = threadIdx.x;
    if (bid < 144) {
        int idx = bid * 256 + tid;           // 36864 total, 4 elems each
        const float* src;
        short* dst;
        if (idx < 4096) {
            int e = idx * 4;
            src = Wq + ((e >> 7) * 256) + (e & 127);
            dst = (short*)(wsb + WS_WQX) + e;
        } else if (idx < 20480) {
            int e = (idx - 4096) * 4;
            src = W1 + e;
            dst = (short*)(wsb + WS_W1) + e;
        } else {
            int e = (idx - 20480) * 4;
            src = W2 + e;
            dst = (short*)(wsb + WS_W2) + e;
        }
        float4 v = *(const float4*)src;
        s16x4 pk;
        pk[0] = f2b(v.x); pk[1] = f2b(v.y); pk[2] = f2b(v.z); pk[3] = f2b(v.w);
        *(s16x4*)dst = pk;
    } else if (bid < 400) {
        int bt = (bid - 144) * 2 + (tid >> 7);
        int f = tid & 127;
        smG[tid] = guid[(size_t)bt * 128 + f];
        __syncthreads();
        const float* wr = Wq + (size_t)f * 256 + 128;
        const float* gg = &smG[(tid >> 7) * 128];
        float acc = bq[f];
        #pragma unroll
        for (int g = 0; g < 128; g += 4) {
            float4 w4 = *(const float4*)(wr + g);
            acc = fmaf(gg[g],     w4.x, acc);
            acc = fmaf(gg[g + 1], w4.y, acc);
            acc = fmaf(gg[g + 2], w4.z, acc);
            acc = fmaf(gg[g + 3], w4.w, acc);
        }
        ((float*)(wsb + WS_QG))[(size_t)bt * 128 + f] = acc;
    } else {
        // prototypes, head h: cols [32h, 32h+32)
        const int h = bid - 400;
        const int base_c = h * 32;
        const int cl = tid & 31, p0 = tid >> 5;   // p0 in 0..7
        const int c = base_c + cl;
        const float* wkr = Wk + (size_t)c * C_;
        const float* wvr = Wv + (size_t)c * C_;
        float ka[4], va[4];
        #pragma unroll
        for (int i = 0; i < 4; ++i) { ka[i] = bk[c]; va[i] = bv[c]; }
        for (int j = 0; j < C_; j += 4) {
            float4 wk4 = *(const float4*)(wkr + j);
            float4 wv4 = *(const float4*)(wvr + j);
            #pragma unroll
            for (int i = 0; i < 4; ++i) {
                float4 pv = *(const float4*)(protos + (size_t)(p0 + 8 * i) * C_ + j);
                ka[i] = fmaf(pv.x, wk4.x, ka[i]); ka[i] = fmaf(pv.y, wk4.y, ka[i]);
                ka[i] = fmaf(pv.z, wk4.z, ka[i]); ka[i] = fmaf(pv.w, wk4.w, ka[i]);
                va[i] = fmaf(pv.x, wv4.x, va[i]); va[i] = fmaf(pv.y, wv4.y, va[i]);
                va[i] = fmaf(pv.z, wv4.z, va[i]); va[i] = fmaf(pv.w, wv4.w, va[i]);
            }
        }
        #pragma unroll
        for (int i = 0; i < 4; ++i) {
            int p = p0 + 8 * i;
            kf_s[p][cl] = ka[i] > 0.f ? ka[i] + 1.f : __expf(ka[i]);
            vv_s[p][cl] = va[i] * (1.f / P_);
        }
        __syncthreads();
        short* kvt = (short*)(wsb + WS_KVT);
        float* ks  = (float*)(wsb + WS_KSUM);
        #pragma unroll
        for (int o = tid; o < 1024; o += 256) {
            int col = o >> 5, d = o & 31;
            float acc = 0.f;
            for (int p = 0; p < P_; ++p)
                acc = fmaf(kf_s[p][d], vv_s[p][col], acc);
            kvt[(base_c + col) * 32 + d] = f2b(acc);
        }
        if (tid < 32) {
            float acc = 0.f;
            for (int p = 0; p < P_; ++p) acc += kf_s[p][tid];
            ks[base_c + tid] = acc;
        }
    }
}

// ---------------------------------------------------------------------------
// main: round-11 champion (238.6 us), byte-exact revert.
// 64 tokens/block, 8 waves; wave w owns features [16w, 16w+16).
// Swapped MFMAs: D'[feat][tok] = W(A) x act(B).
// ---------------------------------------------------------------------------
__global__ __launch_bounds__(512, 8)
void cat_main(const float* __restrict__ x,
              const float* __restrict__ ln1_g, const float* __restrict__ ln1_b,
              const float* __restrict__ ln2_g, const float* __restrict__ ln2_b,
              const float* __restrict__ b1, const float* __restrict__ b2,
              const char* __restrict__ wsb, float* __restrict__ out) {
    __shared__ short bufA[TOK * C_];   // x -> y
    __shared__ short bufB[TOK * C_];   // qf -> h chunks
    __shared__ float mu1[TOK], rs1[TOK];
    __shared__ float zp[TOK][8];
    __shared__ float lnS[TOK][8], lnS2[TOK][8];

    const short* kvt  = (const short*)(wsb + WS_KVT);
    const float* ksum = (const float*)(wsb + WS_KSUM);
    const short* wqx  = (const short*)(wsb + WS_WQX);
    const short* w1b  = (const short*)(wsb + WS_W1);
    const short* w2b  = (const short*)(wsb + WS_W2);
    const float* qg_g = (const float*)(wsb + WS_QG);

    const int tid = threadIdx.x;
    const int w = tid >> 6, l = tid & 63;
    const int lr = l & 15, lg = l >> 4;
    const int bt = blockIdx.z * T_ + blockIdx.y;
    const int hw0 = blockIdx.x * TOK;
    const int frow = w * 16 + lr;          // A-operand feature row
    const int cb0 = w * 16 + lg * 4;       // D-frag feature base

    // ---- stage x -> bufA: 4-channel x 4-token register tile, b64 writes ----
    {
        int cb = tid >> 4, tg = tid & 15;
        float4 v[4];
        #pragma unroll
        for (int i = 0; i < 4; ++i)
            v[i] = *(const float4*)(x + ((size_t)bt * C_ + cb * 4 + i) * HW_
                                    + hw0 + tg * 4);
        #pragma unroll
        for (int j = 0; j < 4; ++j) {
            s16x4 pk;
            pk[0] = f2b(((const float*)&v[0])[j]);
            pk[1] = f2b(((const float*)&v[1])[j]);
            pk[2] = f2b(((const float*)&v[2])[j]);
            pk[3] = f2b(((const float*)&v[3])[j]);
            *(s16x4*)&bufA[swz(tg * 4 + j, cb * 4)] = pk;
        }
    }
    __syncthreads();

    // ---- LN1 stats: 8 threads/token ----
    {
        int tok = tid >> 3, q = tid & 7;
        float s = 0.f, s2 = 0.f;
        #pragma unroll
        for (int j = 0; j < 2; ++j) {
            s16x8 v8 = *(const s16x8*)&bufA[swz(tok, q * 16 + j * 8)];
            #pragma unroll
            for (int e = 0; e < 8; ++e) {
                float v = b2f(v8[e]); s += v; s2 = fmaf(v, v, s2);
            }
        }
        s += __shfl_xor(s, 1); s2 += __shfl_xor(s2, 1);
        s += __shfl_xor(s, 2); s2 += __shfl_xor(s2, 2);
        s += __shfl_xor(s, 4); s2 += __shfl_xor(s2, 4);
        if (q == 0) {
            float mu = s * (1.f / C_);
            mu1[tok] = mu;
            rs1[tok] = rsqrtf(s2 * (1.f / C_) - mu * mu + EPS_LN);
        }
    }

    // ---- Q projection (x part; guidance part precomputed in qg_g) ----
    f32x4 qacc[4];
    #pragma unroll
    for (int mt = 0; mt < 4; ++mt) qacc[mt] = (f32x4){0.f, 0.f, 0.f, 0.f};
    #pragma unroll
    for (int kc = 0; kc < 4; ++kc) {
        bf16x8 aw = *(const bf16x8*)&wqx[frow * C_ + kc * 32 + lg * 8];
        #pragma unroll
        for (int mt = 0; mt < 4; ++mt) {
            bf16x8 bx = *(const bf16x8*)&bufA[swz(mt * 16 + lr, kc * 32 + lg * 8)];
            qacc[mt] = __builtin_amdgcn_mfma_f32_16x16x32_bf16(aw, bx, qacc[mt], 0, 0, 0);
        }
    }

    // ---- qf = elu(q + qg)+1 -> bufB (b64), Z partials ----
    {
        f32x4 qg4 = *(const f32x4*)&qg_g[(size_t)bt * C_ + cb0];
        f32x4 ks4 = *(const f32x4*)&ksum[cb0];
        #pragma unroll
        for (int mt = 0; mt < 4; ++mt) {
            float dp = 0.f;
            s16x4 pk;
            #pragma unroll
            for (int r = 0; r < 4; ++r) {
                float qv = qacc[mt][r] + qg4[r];
                float f = qv > 0.f ? qv + 1.f : __expf(qv);
                dp = fmaf(f, ks4[r], dp);
                pk[r] = f2b(f);
            }
            *(s16x4*)&bufB[swz(mt * 16 + lr, cb0)] = pk;
            dp += __shfl_xor(dp, 16);
            dp += __shfl_xor(dp, 32);
            if (lg == 0) zp[mt * 16 + lr][w] = dp;
        }
    }
    __syncthreads();

    // ---- attention: K=32 (head w>>1) ----
    f32x4 aacc[4];
    {
        const int h = w >> 1;
        bf16x8 aw = *(const bf16x8*)&kvt[frow * 32 + lg * 8];
        #pragma unroll
        for (int mt = 0; mt < 4; ++mt) {
            bf16x8 bq_ = *(const bf16x8*)&bufB[swz(mt * 16 + lr, h * 32 + lg * 8)];
            aacc[mt] = __builtin_amdgcn_mfma_f32_16x16x32_bf16(
                aw, bq_, (f32x4){0.f, 0.f, 0.f, 0.f}, 0, 0, 0);
        }
    }

    // ---- o1 = attn*Z + LN1(x); LN2 partials ----
    f32x4 o1[4];
    {
        f32x4 g1 = *(const f32x4*)&ln1_g[cb0];
        f32x4 bb1 = *(const f32x4*)&ln1_b[cb0];
        #pragma unroll
        for (int mt = 0; mt < 4; ++mt) {
            int tok = mt * 16 + lr;
            f32x4 za = *(const f32x4*)&zp[tok][0];
            f32x4 zb = *(const f32x4*)&zp[tok][4];
            float den = za[0] + za[1] + za[2] + za[3]
                      + zb[0] + zb[1] + zb[2] + zb[3] + EPS_ATTN;
            float zv = (float)P_ * __builtin_amdgcn_rcpf(den);
            s16x4 xv = *(const s16x4*)&bufA[swz(tok, cb0)];
            float mu = mu1[tok], rs = rs1[tok];
            float s = 0.f, s2 = 0.f;
            #pragma unroll
            for (int r = 0; r < 4; ++r) {
                float ln1 = fmaf((b2f(xv[r]) - mu) * rs, g1[r], bb1[r]);
                float v = fmaf(aacc[mt][r], zv, ln1);
                o1[mt][r] = v;
                s += v; s2 = fmaf(v, v, s2);
            }
            s += __shfl_xor(s, 16); s2 += __shfl_xor(s2, 16);
            s += __shfl_xor(s, 32); s2 += __shfl_xor(s2, 32);
            if (lg == 0) { lnS[tok][w] = s; lnS2[tok][w] = s2; }
        }
    }
    __syncthreads();

    // ---- y = LN2(o1) -> bufA ----
    {
        f32x4 g2 = *(const f32x4*)&ln2_g[cb0];
        f32x4 bb2 = *(const f32x4*)&ln2_b[cb0];
        #pragma unroll
        for (int mt = 0; mt < 4; ++mt) {
            int tok = mt * 16 + lr;
            f32x4 sa = *(const f32x4*)&lnS[tok][0];
            f32x4 sb = *(const f32x4*)&lnS[tok][4];
            f32x4 pa = *(const f32x4*)&lnS2[tok][0];
            f32x4 pb = *(const f32x4*)&lnS2[tok][4];
            float ss = sa[0] + sa[1] + sa[2] + sa[3] + sb[0] + sb[1] + sb[2] + sb[3];
            float ss2 = pa[0] + pa[1] + pa[2] + pa[3] + pb[0] + pb[1] + pb[2] + pb[3];
            float mu = ss * (1.f / C_);
            float rs = rsqrtf(ss2 * (1.f / C_) - mu * mu + EPS_LN);
            s16x4 pk;
            #pragma unroll
            for (int r = 0; r < 4; ++r)
                pk[r] = f2b(fmaf((o1[mt][r] - mu) * rs, g2[r], bb2[r]));
            *(s16x4*)&bufA[swz(tok, cb0)] = pk;
        }
    }
    __syncthreads();

    // ---- FFN ----
    f32x4 facc[4];
    {
        f32x4 bv2 = *(const f32x4*)&b2[cb0];
        #pragma unroll
        for (int mt = 0; mt < 4; ++mt)
            #pragma unroll
            for (int r = 0; r < 4; ++r)
                facc[mt][r] = o1[mt][r] + bv2[r];
    }
    for (int ch = 0; ch < 4; ++ch) {
        f32x4 hacc[4];
        #pragma unroll
        for (int mt = 0; mt < 4; ++mt) hacc[mt] = (f32x4){0.f, 0.f, 0.f, 0.f};
        #pragma unroll
        for (int kc = 0; kc < 4; ++kc) {
            bf16x8 aw = *(const bf16x8*)&w1b[(ch * 128 + frow) * C_ + kc * 32 + lg * 8];
            #pragma unroll
            for (int mt = 0; mt < 4; ++mt) {
                bf16x8 by = *(const bf16x8*)&bufA[swz(mt * 16 + lr, kc * 32 + lg * 8)];
                hacc[mt] = __builtin_amdgcn_mfma_f32_16x16x32_bf16(aw, by, hacc[mt], 0, 0, 0);
            }
        }
        f32x4 bb = *(const f32x4*)&b1[ch * 128 + cb0];
        #pragma unroll
        for (int mt = 0; mt < 4; ++mt) {
            s16x4 pk;
            #pragma unroll
            for (int r = 0; r < 4; ++r)
                pk[r] = f2b(gelu_f(hacc[mt][r] + bb[r]));
            *(s16x4*)&bufB[swz(mt * 16 + lr, cb0)] = pk;
        }
        __syncthreads();
        #pragma unroll
        for (int kc = 0; kc < 4; ++kc) {
            bf16x8 aw = *(const bf16x8*)&w2b[frow * FF_ + ch * 128 + kc * 32 + lg * 8];
            #pragma unroll
            for (int mt = 0; mt < 4; ++mt) {
                bf16x8 bh = *(const bf16x8*)&bufB[swz(mt * 16 + lr, kc * 32 + lg * 8)];
                facc[mt] = __builtin_amdgcn_mfma_f32_16x16x32_bf16(aw, bh, facc[mt], 0, 0, 0);
            }
        }
        __syncthreads();
    }

    // ---- epilogue (facc = o1 + ffn + b2) ----
    #pragma unroll
    for (int mt = 0; mt < 4; ++mt) {
        int tok = mt * 16 + lr;
        #pragma unroll
        for (int r = 0; r < 4; ++r)
            out[((size_t)bt * C_ + cb0 + r) * HW_ + hw0 + tok] = facc[mt][r];
    }
}

extern "C" void kernel_launch(void* const* d_in, const int* in_sizes, int n_in,
                              void* d_out, int out_size, void* d_ws, size_t ws_size,
                              hipStream_t stream) {
    (void)in_sizes; (void)n_in; (void)out_size; (void)ws_size;
    const float* x      = (const float*)d_in[0];
    const float* guid   = (const float*)d_in[1];
    const float* protos = (const float*)d_in[2];
    const float* Wq     = (const float*)d_in[3];
    const float* bq     = (const float*)d_in[4];
    const float* Wk     = (const float*)d_in[5];
    const float* bk     = (const float*)d_in[6];
    const float* Wv     = (const float*)d_in[7];
    const float* bv     = (const float*)d_in[8];
    const float* ln1_g  = (const float*)d_in[9];
    const float* ln1_b  = (const float*)d_in[10];
    const float* ln2_g  = (const float*)d_in[11];
    const float* ln2_b  = (const float*)d_in[12];
    const float* W1     = (const float*)d_in[13];
    const float* b1     = (const float*)d_in[14];
    const float* W2     = (const float*)d_in[15];
    const float* b2     = (const float*)d_in[16];
    float* out = (float*)d_out;
    char* wsb  = (char*)d_ws;

    prep_all<<<404, 256, 0, stream>>>(protos, Wk, bk, Wv, bv, Wq, W1, W2,
                                      guid, bq, wsb);
    dim3 grid(HW_ / TOK, T_, B_);
    cat_main<<<grid, 512, 0, stream>>>(x, ln1_g, ln1_b, ln2_g, ln2_b,
                                       b1, b2, wsb, out);
}

// Round 15
// 231.786 us; speedup vs baseline: 1.2263x; 1.0313x over previous
//
#include <hip/hip_runtime.h>
#include <math.h>

#define B_ 4
#define T_ 128
#define C_ 128
#define HW_ 576
#define P_ 32
#define FF_ 512
#define EPS_ATTN 1e-6f
#define EPS_LN 1e-5f
#define TOK 64

typedef __bf16 bf16x8 __attribute__((ext_vector_type(8)));
typedef float f32x4 __attribute__((ext_vector_type(4)));
typedef short s16x8 __attribute__((ext_vector_type(8)));
typedef short s16x4 __attribute__((ext_vector_type(4)));

// ---- ws byte offsets (16B aligned) ----
#define WS_KVT   0        // bf16 [128][32] : kvt[col][d] = KV[col>>5][d][col&31]
#define WS_KSUM  8192     // f32  [128]
#define WS_WQX   8704     // bf16 [128][128]  (x-part of Wq)
#define WS_W1    41472    // bf16 [512][128]
#define WS_W2    172544   // bf16 [128][512]
#define WS_QG    303616   // f32  [512][128]  (guidance projection + bq)

// native RTNE bf16 cvt (compiler packs pairs into v_cvt_pk_bf16_f32)
__device__ __forceinline__ short f2b(float f) {
    return __builtin_bit_cast(short, (__bf16)f);
}
__device__ __forceinline__ float b2f(short s) {
    return __builtin_bit_cast(float, ((unsigned)(unsigned short)s) << 16);
}
// swizzled short-index into [64][128] bf16 tile: XOR 16B granule by (row&7)
__device__ __forceinline__ int swz(int row, int col) {
    return (row << 7) | (col ^ ((row & 7) << 3));
}
// sigmoid-form GELU: v * sigmoid(1.702 v). |err| <= ~0.02 pointwise on h;
// after W2 (random-sign weights, s=0.02) contributes ~0.004 to out.
__device__ __forceinline__ float gelu_f(float v) {
    float e = __expf(-1.702f * v);
    return v * __builtin_amdgcn_rcpf(1.f + e);
}

// ---------------------------------------------------------------------------
// prep: bid 0..143   vectorized weight conversion (4 elems/thread)
//       bid 144..399 guidance projection qg[bt][f] (2 bt per block)
//       bid 400..403 prototypes -> kvt + ksum, split per head (4-way)
// ---------------------------------------------------------------------------
__global__ __launch_bounds__(256)
void prep_all(const float* __restrict__ protos,
              const float* __restrict__ Wk, const float* __restrict__ bk,
              const float* __restrict__ Wv, const float* __restrict__ bv,
              const float* __restrict__ Wq, const float* __restrict__ W1,
              const float* __restrict__ W2, const float* __restrict__ guid,
              const float* __restrict__ bq, char* __restrict__ wsb) {
    __shared__ float smG[256];
    __shared__ float kf_s[P_][32];
    __shared__ float vv_s[P_][32];
    const int bid = blockIdx.x, tid = threadIdx.x;
    if (bid < 144) {
        int idx = bid * 256 + tid;           // 36864 total, 4 elems each
        const float* src;
        short* dst;
        if (idx < 4096) {
            int e = idx * 4;
            src = Wq + ((e >> 7) * 256) + (e & 127);
            dst = (short*)(wsb + WS_WQX) + e;
        } else if (idx < 20480) {
            int e = (idx - 4096) * 4;
            src = W1 + e;
            dst = (short*)(wsb + WS_W1) + e;
        } else {
            int e = (idx - 20480) * 4;
            src = W2 + e;
            dst = (short*)(wsb + WS_W2) + e;
        }
        float4 v = *(const float4*)src;
        s16x4 pk;
        pk[0] = f2b(v.x); pk[1] = f2b(v.y); pk[2] = f2b(v.z); pk[3] = f2b(v.w);
        *(s16x4*)dst = pk;
    } else if (bid < 400) {
        int bt = (bid - 144) * 2 + (tid >> 7);
        int f = tid & 127;
        smG[tid] = guid[(size_t)bt * 128 + f];
        __syncthreads();
        const float* wr = Wq + (size_t)f * 256 + 128;
        const float* gg = &smG[(tid >> 7) * 128];
        float acc = bq[f];
        #pragma unroll
        for (int g = 0; g < 128; g += 4) {
            float4 w4 = *(const float4*)(wr + g);
            acc = fmaf(gg[g],     w4.x, acc);
            acc = fmaf(gg[g + 1], w4.y, acc);
            acc = fmaf(gg[g + 2], w4.z, acc);
            acc = fmaf(gg[g + 3], w4.w, acc);
        }
        ((float*)(wsb + WS_QG))[(size_t)bt * 128 + f] = acc;
    } else {
        // prototypes, head h: cols [32h, 32h+32)
        const int h = bid - 400;
        const int base_c = h * 32;
        const int cl = tid & 31, p0 = tid >> 5;   // p0 in 0..7
        const int c = base_c + cl;
        const float* wkr = Wk + (size_t)c * C_;
        const float* wvr = Wv + (size_t)c * C_;
        float ka[4], va[4];
        #pragma unroll
        for (int i = 0; i < 4; ++i) { ka[i] = bk[c]; va[i] = bv[c]; }
        for (int j = 0; j < C_; j += 4) {
            float4 wk4 = *(const float4*)(wkr + j);
            float4 wv4 = *(const float4*)(wvr + j);
            #pragma unroll
            for (int i = 0; i < 4; ++i) {
                float4 pv = *(const float4*)(protos + (size_t)(p0 + 8 * i) * C_ + j);
                ka[i] = fmaf(pv.x, wk4.x, ka[i]); ka[i] = fmaf(pv.y, wk4.y, ka[i]);
                ka[i] = fmaf(pv.z, wk4.z, ka[i]); ka[i] = fmaf(pv.w, wk4.w, ka[i]);
                va[i] = fmaf(pv.x, wv4.x, va[i]); va[i] = fmaf(pv.y, wv4.y, va[i]);
                va[i] = fmaf(pv.z, wv4.z, va[i]); va[i] = fmaf(pv.w, wv4.w, va[i]);
            }
        }
        #pragma unroll
        for (int i = 0; i < 4; ++i) {
            int p = p0 + 8 * i;
            kf_s[p][cl] = ka[i] > 0.f ? ka[i] + 1.f : __expf(ka[i]);
            vv_s[p][cl] = va[i] * (1.f / P_);
        }
        __syncthreads();
        short* kvt = (short*)(wsb + WS_KVT);
        float* ks  = (float*)(wsb + WS_KSUM);
        #pragma unroll
        for (int o = tid; o < 1024; o += 256) {
            int col = o >> 5, d = o & 31;
            float acc = 0.f;
            for (int p = 0; p < P_; ++p)
                acc = fmaf(kf_s[p][d], vv_s[p][col], acc);
            kvt[(base_c + col) * 32 + d] = f2b(acc);
        }
        if (tid < 32) {
            float acc = 0.f;
            for (int p = 0; p < P_; ++p) acc += kf_s[p][tid];
            ks[base_c + tid] = acc;
        }
    }
}

// ---------------------------------------------------------------------------
// main: round-11 champion + T5 s_setprio(1) around MFMA clusters.
// 64 tokens/block, 8 waves; wave w owns features [16w, 16w+16).
// Swapped MFMAs: D'[feat][tok] = W(A) x act(B).
// ---------------------------------------------------------------------------
__global__ __launch_bounds__(512, 8)
void cat_main(const float* __restrict__ x,
              const float* __restrict__ ln1_g, const float* __restrict__ ln1_b,
              const float* __restrict__ ln2_g, const float* __restrict__ ln2_b,
              const float* __restrict__ b1, const float* __restrict__ b2,
              const char* __restrict__ wsb, float* __restrict__ out) {
    __shared__ short bufA[TOK * C_];   // x -> y
    __shared__ short bufB[TOK * C_];   // qf -> h chunks
    __shared__ float mu1[TOK], rs1[TOK];
    __shared__ float zp[TOK][8];
    __shared__ float lnS[TOK][8], lnS2[TOK][8];

    const short* kvt  = (const short*)(wsb + WS_KVT);
    const float* ksum = (const float*)(wsb + WS_KSUM);
    const short* wqx  = (const short*)(wsb + WS_WQX);
    const short* w1b  = (const short*)(wsb + WS_W1);
    const short* w2b  = (const short*)(wsb + WS_W2);
    const float* qg_g = (const float*)(wsb + WS_QG);

    const int tid = threadIdx.x;
    const int w = tid >> 6, l = tid & 63;
    const int lr = l & 15, lg = l >> 4;
    const int bt = blockIdx.z * T_ + blockIdx.y;
    const int hw0 = blockIdx.x * TOK;
    const int frow = w * 16 + lr;          // A-operand feature row
    const int cb0 = w * 16 + lg * 4;       // D-frag feature base

    // ---- stage x -> bufA: 4-channel x 4-token register tile, b64 writes ----
    {
        int cb = tid >> 4, tg = tid & 15;
        float4 v[4];
        #pragma unroll
        for (int i = 0; i < 4; ++i)
            v[i] = *(const float4*)(x + ((size_t)bt * C_ + cb * 4 + i) * HW_
                                    + hw0 + tg * 4);
        #pragma unroll
        for (int j = 0; j < 4; ++j) {
            s16x4 pk;
            pk[0] = f2b(((const float*)&v[0])[j]);
            pk[1] = f2b(((const float*)&v[1])[j]);
            pk[2] = f2b(((const float*)&v[2])[j]);
            pk[3] = f2b(((const float*)&v[3])[j]);
            *(s16x4*)&bufA[swz(tg * 4 + j, cb * 4)] = pk;
        }
    }
    __syncthreads();

    // ---- LN1 stats: 8 threads/token ----
    {
        int tok = tid >> 3, q = tid & 7;
        float s = 0.f, s2 = 0.f;
        #pragma unroll
        for (int j = 0; j < 2; ++j) {
            s16x8 v8 = *(const s16x8*)&bufA[swz(tok, q * 16 + j * 8)];
            #pragma unroll
            for (int e = 0; e < 8; ++e) {
                float v = b2f(v8[e]); s += v; s2 = fmaf(v, v, s2);
            }
        }
        s += __shfl_xor(s, 1); s2 += __shfl_xor(s2, 1);
        s += __shfl_xor(s, 2); s2 += __shfl_xor(s2, 2);
        s += __shfl_xor(s, 4); s2 += __shfl_xor(s2, 4);
        if (q == 0) {
            float mu = s * (1.f / C_);
            mu1[tok] = mu;
            rs1[tok] = rsqrtf(s2 * (1.f / C_) - mu * mu + EPS_LN);
        }
    }

    // ---- Q projection (x part; guidance part precomputed in qg_g) ----
    f32x4 qacc[4];
    #pragma unroll
    for (int mt = 0; mt < 4; ++mt) qacc[mt] = (f32x4){0.f, 0.f, 0.f, 0.f};
    __builtin_amdgcn_s_setprio(1);
    #pragma unroll
    for (int kc = 0; kc < 4; ++kc) {
        bf16x8 aw = *(const bf16x8*)&wqx[frow * C_ + kc * 32 + lg * 8];
        #pragma unroll
        for (int mt = 0; mt < 4; ++mt) {
            bf16x8 bx = *(const bf16x8*)&bufA[swz(mt * 16 + lr, kc * 32 + lg * 8)];
            qacc[mt] = __builtin_amdgcn_mfma_f32_16x16x32_bf16(aw, bx, qacc[mt], 0, 0, 0);
        }
    }
    __builtin_amdgcn_s_setprio(0);

    // ---- qf = elu(q + qg)+1 -> bufB (b64), Z partials ----
    {
        f32x4 qg4 = *(const f32x4*)&qg_g[(size_t)bt * C_ + cb0];
        f32x4 ks4 = *(const f32x4*)&ksum[cb0];
        #pragma unroll
        for (int mt = 0; mt < 4; ++mt) {
            float dp = 0.f;
            s16x4 pk;
            #pragma unroll
            for (int r = 0; r < 4; ++r) {
                float qv = qacc[mt][r] + qg4[r];
                float f = qv > 0.f ? qv + 1.f : __expf(qv);
                dp = fmaf(f, ks4[r], dp);
                pk[r] = f2b(f);
            }
            *(s16x4*)&bufB[swz(mt * 16 + lr, cb0)] = pk;
            dp += __shfl_xor(dp, 16);
            dp += __shfl_xor(dp, 32);
            if (lg == 0) zp[mt * 16 + lr][w] = dp;
        }
    }
    __syncthreads();

    // ---- attention: K=32 (head w>>1) ----
    f32x4 aacc[4];
    {
        const int h = w >> 1;
        bf16x8 aw = *(const bf16x8*)&kvt[frow * 32 + lg * 8];
        __builtin_amdgcn_s_setprio(1);
        #pragma unroll
        for (int mt = 0; mt < 4; ++mt) {
            bf16x8 bq_ = *(const bf16x8*)&bufB[swz(mt * 16 + lr, h * 32 + lg * 8)];
            aacc[mt] = __builtin_amdgcn_mfma_f32_16x16x32_bf16(
                aw, bq_, (f32x4){0.f, 0.f, 0.f, 0.f}, 0, 0, 0);
        }
        __builtin_amdgcn_s_setprio(0);
    }

    // ---- o1 = attn*Z + LN1(x); LN2 partials ----
    f32x4 o1[4];
    {
        f32x4 g1 = *(const f32x4*)&ln1_g[cb0];
        f32x4 bb1 = *(const f32x4*)&ln1_b[cb0];
        #pragma unroll
        for (int mt = 0; mt < 4; ++mt) {
            int tok = mt * 16 + lr;
            f32x4 za = *(const f32x4*)&zp[tok][0];
            f32x4 zb = *(const f32x4*)&zp[tok][4];
            float den = za[0] + za[1] + za[2] + za[3]
                      + zb[0] + zb[1] + zb[2] + zb[3] + EPS_ATTN;
            float zv = (float)P_ * __builtin_amdgcn_rcpf(den);
            s16x4 xv = *(const s16x4*)&bufA[swz(tok, cb0)];
            float mu = mu1[tok], rs = rs1[tok];
            float s = 0.f, s2 = 0.f;
            #pragma unroll
            for (int r = 0; r < 4; ++r) {
                float ln1 = fmaf((b2f(xv[r]) - mu) * rs, g1[r], bb1[r]);
                float v = fmaf(aacc[mt][r], zv, ln1);
                o1[mt][r] = v;
                s += v; s2 = fmaf(v, v, s2);
            }
            s += __shfl_xor(s, 16); s2 += __shfl_xor(s2, 16);
            s += __shfl_xor(s, 32); s2 += __shfl_xor(s2, 32);
            if (lg == 0) { lnS[tok][w] = s; lnS2[tok][w] = s2; }
        }
    }
    __syncthreads();

    // ---- y = LN2(o1) -> bufA ----
    {
        f32x4 g2 = *(const f32x4*)&ln2_g[cb0];
        f32x4 bb2 = *(const f32x4*)&ln2_b[cb0];
        #pragma unroll
        for (int mt = 0; mt < 4; ++mt) {
            int tok = mt * 16 + lr;
            f32x4 sa = *(const f32x4*)&lnS[tok][0];
            f32x4 sb = *(const f32x4*)&lnS[tok][4];
            f32x4 pa = *(const f32x4*)&lnS2[tok][0];
            f32x4 pb = *(const f32x4*)&lnS2[tok][4];
            float ss = sa[0] + sa[1] + sa[2] + sa[3] + sb[0] + sb[1] + sb[2] + sb[3];
            float ss2 = pa[0] + pa[1] + pa[2] + pa[3] + pb[0] + pb[1] + pb[2] + pb[3];
            float mu = ss * (1.f / C_);
            float rs = rsqrtf(ss2 * (1.f / C_) - mu * mu + EPS_LN);
            s16x4 pk;
            #pragma unroll
            for (int r = 0; r < 4; ++r)
                pk[r] = f2b(fmaf((o1[mt][r] - mu) * rs, g2[r], bb2[r]));
            *(s16x4*)&bufA[swz(tok, cb0)] = pk;
        }
    }
    __syncthreads();

    // ---- FFN ----
    f32x4 facc[4];
    {
        f32x4 bv2 = *(const f32x4*)&b2[cb0];
        #pragma unroll
        for (int mt = 0; mt < 4; ++mt)
            #pragma unroll
            for (int r = 0; r < 4; ++r)
                facc[mt][r] = o1[mt][r] + bv2[r];
    }
    for (int ch = 0; ch < 4; ++ch) {
        f32x4 hacc[4];
        #pragma unroll
        for (int mt = 0; mt < 4; ++mt) hacc[mt] = (f32x4){0.f, 0.f, 0.f, 0.f};
        __builtin_amdgcn_s_setprio(1);
        #pragma unroll
        for (int kc = 0; kc < 4; ++kc) {
            bf16x8 aw = *(const bf16x8*)&w1b[(ch * 128 + frow) * C_ + kc * 32 + lg * 8];
            #pragma unroll
            for (int mt = 0; mt < 4; ++mt) {
                bf16x8 by = *(const bf16x8*)&bufA[swz(mt * 16 + lr, kc * 32 + lg * 8)];
                hacc[mt] = __builtin_amdgcn_mfma_f32_16x16x32_bf16(aw, by, hacc[mt], 0, 0, 0);
            }
        }
        __builtin_amdgcn_s_setprio(0);
        f32x4 bb = *(const f32x4*)&b1[ch * 128 + cb0];
        #pragma unroll
        for (int mt = 0; mt < 4; ++mt) {
            s16x4 pk;
            #pragma unroll
            for (int r = 0; r < 4; ++r)
                pk[r] = f2b(gelu_f(hacc[mt][r] + bb[r]));
            *(s16x4*)&bufB[swz(mt * 16 + lr, cb0)] = pk;
        }
        __syncthreads();
        __builtin_amdgcn_s_setprio(1);
        #pragma unroll
        for (int kc = 0; kc < 4; ++kc) {
            bf16x8 aw = *(const bf16x8*)&w2b[frow * FF_ + ch * 128 + kc * 32 + lg * 8];
            #pragma unroll
            for (int mt = 0; mt < 4; ++mt) {
                bf16x8 bh = *(const bf16x8*)&bufB[swz(mt * 16 + lr, kc * 32 + lg * 8)];
                facc[mt] = __builtin_amdgcn_mfma_f32_16x16x32_bf16(aw, bh, facc[mt], 0, 0, 0);
            }
        }
        __builtin_amdgcn_s_setprio(0);
        __syncthreads();
    }

    // ---- epilogue (facc = o1 + ffn + b2) ----
    #pragma unroll
    for (int mt = 0; mt < 4; ++mt) {
        int tok = mt * 16 + lr;
        #pragma unroll
        for (int r = 0; r < 4; ++r)
            out[((size_t)bt * C_ + cb0 + r) * HW_ + hw0 + tok] = facc[mt][r];
    }
}

extern "C" void kernel_launch(void* const* d_in, const int* in_sizes, int n_in,
                              void* d_out, int out_size, void* d_ws, size_t ws_size,
                              hipStream_t stream) {
    (void)in_sizes; (void)n_in; (void)out_size; (void)ws_size;
    const float* x      = (const float*)d_in[0];
    const float* guid   = (const float*)d_in[1];
    const float* protos = (const float*)d_in[2];
    const float* Wq     = (const float*)d_in[3];
    const float* bq     = (const float*)d_in[4];
    const float* Wk     = (const float*)d_in[5];
    const float* bk     = (const float*)d_in[6];
    const float* Wv     = (const float*)d_in[7];
    const float* bv     = (const float*)d_in[8];
    const float* ln1_g  = (const float*)d_in[9];
    const float* ln1_b  = (const float*)d_in[10];
    const float* ln2_g  = (const float*)d_in[11];
    const float* ln2_b  = (const float*)d_in[12];
    const float* W1     = (const float*)d_in[13];
    const float* b1     = (const float*)d_in[14];
    const float* W2     = (const float*)d_in[15];
    const float* b2     = (const float*)d_in[16];
    float* out = (float*)d_out;
    char* wsb  = (char*)d_ws;

    prep_all<<<404, 256, 0, stream>>>(protos, Wk, bk, Wv, bv, Wq, W1, W2,
                                      guid, bq, wsb);
    dim3 grid(HW_ / TOK, T_, B_);
    cat_main<<<grid, 512, 0, stream>>>(x, ln1_g, ln1_b, ln2_g, ln2_b,
                                       b1, b2, wsb, out);
}